// Round 2
// baseline (302.103 us; speedup 1.0000x reference)
//
#include <hip/hip_runtime.h>
#include <hip/hip_bf16.h>

#define NNODE 512
#define NEDGE 16384
#define INLEN 17929
#define K1    1056   // 32 (u·S) + 512 (dist) + 512 (markov)

// ---- workspace layout (offsets in floats) ----
#define WS_EA      0         // 16384  per-edge ea
#define WS_CSRC    16384     // 16384  csr src (int)
#define WS_CEA     32768     // 16384  csr ea
#define WS_DEG     49152     // 512 (int)
#define WS_STARTS  49664     // 512 (int)
#define WS_CURSOR  50176     // 512 (int)
#define WS_LATTR   50688     // 512
#define WS_LSUM    51200     // 512
#define WS_MM      51712     // 2 (int bits: min,max of dist)
#define WS_STOPV   51716     // 512
#define WS_H       52480     // 512*256 h (per-layer)
#define WS_X1      183552    // 512*256
#define WS_X2      314624    // 512*256
#define WS_ASRC    445696    // 512*8
#define WS_ADST    449792    // 512*8
#define WS_UV      453888    // 512*64 (u | v)
#define WS_S       486656    // 512*32
#define WS_K       503040    // 512
#define WS_APACK   503552    // 512*1056
#define WS_BPACK   1044224   // 512*1056
#define WS_OUT1    1584896   // 512*512
#define WS_WESF    1847040   // 64*256
// total ≈ 1.864M floats ≈ 7.5 MB

// ---------------- init: zero atomics targets, scatter stop vector ----------
__global__ void k_init(float* ws, const int* __restrict__ stops){
  int t = threadIdx.x;
  ((int*)(ws+WS_DEG))[t]    = 0;
  ((int*)(ws+WS_CURSOR))[t] = 0;
  ws[WS_LSUM+t]  = 0.f;
  ws[WS_STOPV+t] = 0.f;
  if (t==0){ ((int*)(ws+WS_MM))[0]=0x7f7fffff; ((int*)(ws+WS_MM))[1]=0; }
  __syncthreads();
  if (t<256) ws[WS_STOPV + stops[t]] = 1.0f;
}

// ---------------- pack Wes into u|v layout: WESF[k,c]=Wes[k,c], WESF[32+k,c]=Wes[k,256+c]
__global__ void k_packwes(const float* __restrict__ Wes, float* ws){
  int idx = blockIdx.x*256 + threadIdx.x;       // 64 blocks -> 16384
  int k = idx>>8, c = idx&255;
  ws[WS_WESF+idx] = (k<32) ? Wes[k*512+c] : Wes[(k-32)*512+256+c];
}

// ---------------- dist min/max (dist>=0 so int-compare atomics valid) ------
__global__ void k_minmax(const float* __restrict__ dist, float* ws){
  __shared__ float smn[256], smx[256];
  int tid = threadIdx.x;
  float mn = 3.4e38f, mx = -3.4e38f;
  for (int idx = blockIdx.x*256+tid; idx < NNODE*NNODE; idx += 256*256){
    float v = dist[idx]; mn = fminf(mn,v); mx = fmaxf(mx,v);
  }
  smn[tid]=mn; smx[tid]=mx; __syncthreads();
  for (int off=128; off; off>>=1){
    if (tid<off){ smn[tid]=fminf(smn[tid],smn[tid+off]); smx[tid]=fmaxf(smx[tid],smx[tid+off]); }
    __syncthreads();
  }
  if (tid==0){
    atomicMin((int*)(ws+WS_MM),   __float_as_int(smn[0]));
    atomicMax((int*)(ws+WS_MM)+1, __float_as_int(smx[0]));
  }
}

// ---------------- edges: gather ea, degree count, loop-attr sums -----------
__global__ void k_edge(const int* __restrict__ eidx, const float* __restrict__ markov, float* ws){
  int e = blockIdx.x*256 + threadIdx.x;
  int r = eidx[e], c = eidx[NEDGE+e];
  float a = markov[r*NNODE + c];
  ws[WS_EA+e] = a;
  atomicAdd((int*)(ws+WS_DEG)+c, 1);
  atomicAdd(ws+WS_LSUM+c, a);
}

// ---------------- exclusive scan of deg + loop_attr ------------------------
__global__ void k_scan(float* ws){
  __shared__ int sc[512];
  int t = threadIdx.x;
  int* deg = (int*)(ws+WS_DEG);
  int d = deg[t];
  sc[t] = d; __syncthreads();
  for (int off=1; off<512; off<<=1){
    int v = (t>=off) ? sc[t-off] : 0; __syncthreads();
    sc[t] += v; __syncthreads();
  }
  ((int*)(ws+WS_STARTS))[t] = sc[t]-d;
  ws[WS_LATTR+t] = ws[WS_LSUM+t] / (float)(d>1 ? d : 1);
}

// ---------------- CSR scatter ----------------------------------------------
__global__ void k_scatter(const int* __restrict__ eidx, float* ws){
  int e = blockIdx.x*256 + threadIdx.x;
  int c = eidx[NEDGE+e];
  int p = ((int*)(ws+WS_STARTS))[c] + atomicAdd((int*)(ws+WS_CURSOR)+c, 1);
  ((int*)(ws+WS_CSRC))[p] = eidx[e];
  ws[WS_CEA+p] = ws[WS_EA+e];
}

// ---------------- layer-1 h = demand[i] * W1 (rank-1) ----------------------
__global__ void k_h1(const float* __restrict__ demand, const float* __restrict__ W1, float* __restrict__ hbuf){
  hbuf[blockIdx.x*256 + threadIdx.x] = demand[blockIdx.x] * W1[threadIdx.x];
}

// ---------------- per-node attention logits a_src/a_dst --------------------
__global__ void k_a(const float* __restrict__ hbuf, const float* __restrict__ att_s,
                    const float* __restrict__ att_d, float* __restrict__ asrc, float* __restrict__ adst){
  int i = blockIdx.x, tid = threadIdx.x, hd = tid>>5, c = tid&31;
  float hv = hbuf[i*256+tid];
  float ps = hv * att_s[tid];
  float pd = hv * att_d[tid];
  for (int off=16; off; off>>=1){ ps += __shfl_down(ps,off,32); pd += __shfl_down(pd,off,32); }
  if (c==0){ asrc[i*8+hd]=ps; adst[i*8+hd]=pd; }
}

// ---------------- GAT softmax + aggregate, one block per target ------------
__global__ __launch_bounds__(256)
void k_agg(const float* __restrict__ hbuf, const float* __restrict__ asrc,
           const float* __restrict__ adst, const int* __restrict__ csrc,
           const float* __restrict__ cea, const int* __restrict__ starts,
           const int* __restrict__ deg, const float* __restrict__ lattr,
           const float* __restrict__ We, const float* __restrict__ atte,
           const float* __restrict__ bvec, float* __restrict__ xout){
  int t = blockIdx.x, tid = threadIdx.x, hd = tid>>5;
  __shared__ float AE[8], m[8], den[8], sw[8];
  __shared__ float w[32*8];
  if (tid < 8){
    float s = 0.f;
    for (int c2=0;c2<32;c2++) s += We[tid*32+c2] * atte[tid*32+c2];
    AE[tid] = s;
  }
  __syncthreads();
  int d = deg[t], s0 = starts[t];
  if (tid < 8){
    float adt = adst[t*8+tid], ae = AE[tid];
    float aself = asrc[t*8+tid] + adt + lattr[t]*ae;
    aself = aself>=0.f ? aself : 0.2f*aself;
    float mm = aself;
    for (int e=0;e<d;e++){
      float a = asrc[csrc[s0+e]*8+tid] + adt + cea[s0+e]*ae;
      a = a>=0.f ? a : 0.2f*a;
      mm = fmaxf(mm, a);
    }
    float dd = __expf(aself-mm);
    for (int e=0;e<d;e++){
      float a = asrc[csrc[s0+e]*8+tid] + adt + cea[s0+e]*ae;
      a = a>=0.f ? a : 0.2f*a;
      dd += __expf(a-mm);
    }
    dd += 1e-16f;
    m[tid]=mm; den[tid]=dd; sw[tid]=__expf(aself-mm)/dd;
  }
  __syncthreads();
  float acc = sw[hd] * hbuf[t*256+tid];        // self-loop (src = t)
  for (int e0=0; e0<d; e0+=32){
    int ce = d-e0 < 32 ? d-e0 : 32;
    int el = tid>>3, h2 = tid&7;
    if (el < ce){
      int src = csrc[s0+e0+el];
      float a = asrc[src*8+h2] + adst[t*8+h2] + cea[s0+e0+el]*AE[h2];
      a = a>=0.f ? a : 0.2f*a;
      w[el*8+h2] = __expf(a-m[h2]) / den[h2];
    }
    __syncthreads();
    for (int e=0;e<ce;e++){
      int src = csrc[s0+e0+e];
      acc += w[e*8+hd] * hbuf[src*256+tid];
    }
    __syncthreads();
  }
  xout[t*256+tid] = fmaxf(acc + bvec[tid], 0.f);   // + bias, relu (outer)
}

// ---------------- S[o,k], K[o] from streaming Wc1 --------------------------
__global__ __launch_bounds__(256)
void k_sk(const float* __restrict__ Wc1, const float* __restrict__ bc1,
          const float* __restrict__ bes, const float* __restrict__ Wweek,
          const float* __restrict__ Wcap, const float* __restrict__ Wveh,
          const int* __restrict__ wd, const int* __restrict__ vh,
          const int* __restrict__ cp, float* ws){
  int o = blockIdx.x, tid = threadIdx.x;
  __shared__ float besf[32];
  __shared__ float red[256];
  if (tid<32) besf[tid] = bes[tid];
  __syncthreads();
  const float* wr = Wc1 + (size_t)o*INLEN;
  const float* UV = ws + WS_UV;
  float sP = 0.f, tP = 0.f;
  for (int idx=tid; idx<16384; idx+=256){        // thread's k-lane fixed: idx&31 == tid&31
    float wv = wr[idx];
    sP += wv;
    tP += wv * (UV[((idx>>5)<<6) + 32 + (idx&31)] + besf[idx&31]);  // v[j,k]+bes[k]
  }
  for (int j=tid; j<512; j+=256) tP += ws[WS_STOPV+j] * wr[17417+j];
  if (tid < 9){
    int g = tid/3, f = tid-g*3;
    float sv = (g==0) ? Wweek[wd[0]*3+f]
             : (g==1) ? Wcap[cp[0]*3+f]
                      : Wveh[vh[0]*3+f];
    tP += sv * wr[17408+tid];
  }
  red[tid] = sP; __syncthreads();
  if (tid<32){ float s=0.f; for (int q=0;q<8;q++) s += red[tid+32*q]; ws[WS_S+o*32+tid] = s; }
  __syncthreads();
  red[tid] = tP; __syncthreads();
  for (int off=128; off; off>>=1){ if (tid<off) red[tid] += red[tid+off]; __syncthreads(); }
  if (tid==0) ws[WS_K+o] = red[0] + bc1[o];
}

// ---------------- pack A = [u | dist_norm | markov] ------------------------
__global__ void k_packA(const float* __restrict__ dist, const float* __restrict__ markov, float* ws){
  int i = blockIdx.x, tid = threadIdx.x;
  float mn = __int_as_float(((int*)(ws+WS_MM))[0]);
  float mx = __int_as_float(((int*)(ws+WS_MM))[1]);
  float inv = 1.0f/(mx-mn);
  for (int j=tid; j<K1; j+=256){
    float v;
    if (j<32)       v = ws[WS_UV + i*64 + j];
    else if (j<544) v = (dist[i*512 + j-32] - mn) * inv;
    else            v = markov[i*512 + j-544];
    ws[WS_APACK + (size_t)i*K1 + j] = v;
  }
}

// ---------------- pack B = [S | Wc1_dist | Wc1_markov] ---------------------
__global__ void k_packB(const float* __restrict__ Wc1, float* ws){
  int o = blockIdx.x, tid = threadIdx.x;
  for (int j=tid; j<K1; j+=256){
    float v = (j<32) ? ws[WS_S+o*32+j] : Wc1[(size_t)o*INLEN + 16384 + (j-32)];
    ws[WS_BPACK + (size_t)o*K1 + j] = v;
  }
}

// ---------------- generic f32 GEMM: C = A(MxK) · B(NxK)^T + bias -----------
template<bool RELU>
__global__ __launch_bounds__(256)
void gemm32(const float* __restrict__ A, const float* __restrict__ B,
            const float* __restrict__ bias, float* __restrict__ C,
            int M, int Nn, int K){
  __shared__ float As[32][34];
  __shared__ float Bs[32][34];
  const int tid = threadIdx.x;
  const int bm = blockIdx.y*32, bn = blockIdx.x*32;
  const int lr = tid>>3, lq = tid&7;
  const int tx = tid&15, ty = tid>>4;
  float a00=0.f, a01=0.f, a10=0.f, a11=0.f;
  const float* Ab = A + (size_t)(bm+lr)*K + 4*lq;
  const float* Bb = B + (size_t)(bn+lr)*K + 4*lq;
  for (int k0=0; k0<K; k0+=32){
    float4 av = *(const float4*)(Ab + k0);
    float4 bv = *(const float4*)(Bb + k0);
    As[4*lq+0][lr]=av.x; As[4*lq+1][lr]=av.y; As[4*lq+2][lr]=av.z; As[4*lq+3][lr]=av.w;
    Bs[4*lq+0][lr]=bv.x; Bs[4*lq+1][lr]=bv.y; Bs[4*lq+2][lr]=bv.z; Bs[4*lq+3][lr]=bv.w;
    __syncthreads();
    #pragma unroll
    for (int kk=0; kk<32; kk++){
      float2 a2 = *(const float2*)&As[kk][2*ty];
      float2 b2 = *(const float2*)&Bs[kk][2*tx];
      a00 += a2.x*b2.x; a01 += a2.x*b2.y; a10 += a2.y*b2.x; a11 += a2.y*b2.y;
    }
    __syncthreads();
  }
  int m0 = bm+2*ty, n0 = bn+2*tx;
  float bi0 = bias ? bias[n0]   : 0.f;
  float bi1 = bias ? bias[n0+1] : 0.f;
  float v00=a00+bi0, v01=a01+bi1, v10=a10+bi0, v11=a11+bi1;
  if (RELU){ v00=fmaxf(v00,0.f); v01=fmaxf(v01,0.f); v10=fmaxf(v10,0.f); v11=fmaxf(v11,0.f); }
  C[(size_t)m0*Nn+n0]       = v00;
  C[(size_t)m0*Nn+n0+1]     = v01;
  C[(size_t)(m0+1)*Nn+n0]   = v10;
  C[(size_t)(m0+1)*Nn+n0+1] = v11;
}

extern "C" void kernel_launch(void* const* d_in, const int* in_sizes, int n_in,
                              void* d_out, int out_size, void* d_ws, size_t ws_size,
                              hipStream_t stream){
  const float* dist   = (const float*)d_in[0];
  const float* markov = (const float*)d_in[1];
  const float* demand = (const float*)d_in[2];
  const float* Wweek  = (const float*)d_in[3];
  const float* Wcap   = (const float*)d_in[4];
  const float* Wveh   = (const float*)d_in[5];
  const float* g1W    = (const float*)d_in[6];
  const float* g1as   = (const float*)d_in[7];
  const float* g1ad   = (const float*)d_in[8];
  const float* g1We   = (const float*)d_in[9];
  const float* g1ae   = (const float*)d_in[10];
  const float* g1b    = (const float*)d_in[11];
  const float* g2W    = (const float*)d_in[12];
  const float* g2as   = (const float*)d_in[13];
  const float* g2ad   = (const float*)d_in[14];
  const float* g2We   = (const float*)d_in[15];
  const float* g2ae   = (const float*)d_in[16];
  const float* g2b    = (const float*)d_in[17];
  const float* Wes    = (const float*)d_in[18];
  const float* bes    = (const float*)d_in[19];
  const float* Wc1    = (const float*)d_in[20];
  const float* bc1    = (const float*)d_in[21];
  const float* Wc2    = (const float*)d_in[22];
  const float* bc2    = (const float*)d_in[23];
  const int*   stops  = (const int*)d_in[24];
  const int*   eidx   = (const int*)d_in[25];
  const int*   wd     = (const int*)d_in[26];
  const int*   vh     = (const int*)d_in[27];
  const int*   cp     = (const int*)d_in[28];
  float* out = (float*)d_out;
  float* ws = (float*)d_ws;

  const int*   csrc   = (const int*)(ws+WS_CSRC);
  const float* cea    = ws+WS_CEA;
  const int*   starts = (const int*)(ws+WS_STARTS);
  const int*   deg    = (const int*)(ws+WS_DEG);
  const float* lattr  = ws+WS_LATTR;

  // graph prep + misc
  k_init<<<1,512,0,stream>>>(ws, stops);
  k_packwes<<<64,256,0,stream>>>(Wes, ws);
  k_minmax<<<256,256,0,stream>>>(dist, ws);
  k_edge<<<64,256,0,stream>>>(eidx, markov, ws);
  k_scan<<<1,512,0,stream>>>(ws);
  k_scatter<<<64,256,0,stream>>>(eidx, ws);

  // GAT layer 1 (input dim 1, rank-1 h)
  k_h1<<<512,256,0,stream>>>(demand, g1W, ws+WS_H);
  k_a<<<512,256,0,stream>>>(ws+WS_H, g1as, g1ad, ws+WS_ASRC, ws+WS_ADST);
  k_agg<<<512,256,0,stream>>>(ws+WS_H, ws+WS_ASRC, ws+WS_ADST, csrc, cea, starts, deg, lattr,
                              g1We, g1ae, g1b, ws+WS_X1);

  // GAT layer 2: h = x1 @ W2^T  (g2W is 256x256 row-major, stride == K)
  gemm32<false><<<dim3(8,16),256,0,stream>>>(ws+WS_X1, g2W, nullptr, ws+WS_H, 512, 256, 256);
  k_a<<<512,256,0,stream>>>(ws+WS_H, g2as, g2ad, ws+WS_ASRC, ws+WS_ADST);
  k_agg<<<512,256,0,stream>>>(ws+WS_H, ws+WS_ASRC, ws+WS_ADST, csrc, cea, starts, deg, lattr,
                              g2We, g2ae, g2b, ws+WS_X2);

  // u|v = x2 @ [WesL|WesR]^T  (512x64)
  gemm32<false><<<dim3(2,16),256,0,stream>>>(ws+WS_X2, ws+WS_WESF, nullptr, ws+WS_UV, 512, 64, 256);

  // decoder: S/K fold of Wc1, pack, two GEMMs
  k_sk<<<512,256,0,stream>>>(Wc1, bc1, bes, Wweek, Wcap, Wveh, wd, vh, cp, ws);
  k_packA<<<512,256,0,stream>>>(dist, markov, ws);
  k_packB<<<512,256,0,stream>>>(Wc1, ws);
  gemm32<true><<<dim3(16,16),256,0,stream>>>(ws+WS_APACK, ws+WS_BPACK, ws+WS_K,
                                             ws+WS_OUT1, 512, 512, K1);
  gemm32<false><<<dim3(16,16),256,0,stream>>>(ws+WS_OUT1, Wc2, bc2, out, 512, 512, 512);
}

// Round 3
// 256.774 us; speedup vs baseline: 1.1765x; 1.1765x over previous
//
#include <hip/hip_runtime.h>
#include <hip/hip_bf16.h>

typedef __hip_bfloat16 bf16;
typedef __attribute__((ext_vector_type(8))) short bf16x8;
typedef __attribute__((ext_vector_type(4))) float f32x4;

#define NNODE 512
#define NEDGE 16384
#define INLEN 17929
#define K1    1056   // 32 (u·S) + 512 (dist) + 512 (markov)

// ---- workspace layout (offsets in floats) ----
#define WS_EA      0         // 16384  per-edge ea
#define WS_CSRC    16384     // 16384  csr src (int)
#define WS_CEA     32768     // 16384  csr ea
#define WS_DEG     49152     // 512 (int)
#define WS_STARTS  49664     // 512 (int)
#define WS_CURSOR  50176     // 512 (int)
#define WS_LATTR   50688     // 512
#define WS_LSUM    51200     // 512
#define WS_MM      51712     // 2 (int bits: min,max of dist)
#define WS_STOPV   51716     // 512
#define WS_H       52480     // 512*256 h (per-layer)
#define WS_X1      183552    // 512*256
#define WS_X2      314624    // 512*256
#define WS_ASRC    445696    // 512*8
#define WS_ADST    449792    // 512*8
#define WS_UV      453888    // 512*64 (u | v)
#define WS_S       486656    // 512*32
#define WS_K       503040    // 512
#define WS_APACK   503552    // 512*1056 bf16
#define WS_BPACK   1044224   // 512*1056 bf16
#define WS_OUT1    1584896   // 512*512 bf16
#define WS_WESF    1847040   // 64*256 f32
#define WS_WC2B    1863424   // 512*512 bf16 (131072 floats)

// ---------------- init: zero atomics targets, scatter stop vector ----------
__global__ void k_init(float* ws, const int* __restrict__ stops){
  int t = threadIdx.x;
  ((int*)(ws+WS_DEG))[t]    = 0;
  ((int*)(ws+WS_CURSOR))[t] = 0;
  ws[WS_LSUM+t]  = 0.f;
  ws[WS_STOPV+t] = 0.f;
  if (t==0){ ((int*)(ws+WS_MM))[0]=0x7f7fffff; ((int*)(ws+WS_MM))[1]=0; }
  __syncthreads();
  if (t<256) ws[WS_STOPV + stops[t]] = 1.0f;
}

// ---------------- pack Wes into u|v layout -------------------------------
__global__ void k_packwes(const float* __restrict__ Wes, float* ws){
  int idx = blockIdx.x*256 + threadIdx.x;       // 64 blocks -> 16384
  int k = idx>>8, c = idx&255;
  ws[WS_WESF+idx] = (k<32) ? Wes[k*512+c] : Wes[(k-32)*512+256+c];
}

// ---------------- dist min/max (dist>=0 so int-compare atomics valid) ------
__global__ void k_minmax(const float* __restrict__ dist, float* ws){
  __shared__ float smn[256], smx[256];
  int tid = threadIdx.x;
  float mn = 3.4e38f, mx = -3.4e38f;
  for (int idx = blockIdx.x*256+tid; idx < NNODE*NNODE; idx += 256*256){
    float v = dist[idx]; mn = fminf(mn,v); mx = fmaxf(mx,v);
  }
  smn[tid]=mn; smx[tid]=mx; __syncthreads();
  for (int off=128; off; off>>=1){
    if (tid<off){ smn[tid]=fminf(smn[tid],smn[tid+off]); smx[tid]=fmaxf(smx[tid],smx[tid+off]); }
    __syncthreads();
  }
  if (tid==0){
    atomicMin((int*)(ws+WS_MM),   __float_as_int(smn[0]));
    atomicMax((int*)(ws+WS_MM)+1, __float_as_int(smx[0]));
  }
}

// ---------------- edges: gather ea, degree count, loop-attr sums -----------
__global__ void k_edge(const int* __restrict__ eidx, const float* __restrict__ markov, float* ws){
  int e = blockIdx.x*256 + threadIdx.x;
  int r = eidx[e], c = eidx[NEDGE+e];
  float a = markov[r*NNODE + c];
  ws[WS_EA+e] = a;
  atomicAdd((int*)(ws+WS_DEG)+c, 1);
  atomicAdd(ws+WS_LSUM+c, a);
}

// ---------------- exclusive scan of deg + loop_attr ------------------------
__global__ void k_scan(float* ws){
  __shared__ int sc[512];
  int t = threadIdx.x;
  int* deg = (int*)(ws+WS_DEG);
  int d = deg[t];
  sc[t] = d; __syncthreads();
  for (int off=1; off<512; off<<=1){
    int v = (t>=off) ? sc[t-off] : 0; __syncthreads();
    sc[t] += v; __syncthreads();
  }
  ((int*)(ws+WS_STARTS))[t] = sc[t]-d;
  ws[WS_LATTR+t] = ws[WS_LSUM+t] / (float)(d>1 ? d : 1);
}

// ---------------- CSR scatter ----------------------------------------------
__global__ void k_scatter(const int* __restrict__ eidx, float* ws){
  int e = blockIdx.x*256 + threadIdx.x;
  int c = eidx[NEDGE+e];
  int p = ((int*)(ws+WS_STARTS))[c] + atomicAdd((int*)(ws+WS_CURSOR)+c, 1);
  ((int*)(ws+WS_CSRC))[p] = eidx[e];
  ws[WS_CEA+p] = ws[WS_EA+e];
}

// ---------------- fused layer-1 h + attention logits -----------------------
__global__ void k_h1a(const float* __restrict__ demand, const float* __restrict__ W1,
                      const float* __restrict__ att_s, const float* __restrict__ att_d,
                      float* __restrict__ hbuf, float* __restrict__ asrc, float* __restrict__ adst){
  int i = blockIdx.x, tid = threadIdx.x, hd = tid>>5, c = tid&31;
  float hv = demand[i] * W1[tid];
  hbuf[i*256+tid] = hv;
  float ps = hv * att_s[tid];
  float pd = hv * att_d[tid];
  for (int off=16; off; off>>=1){ ps += __shfl_down(ps,off,32); pd += __shfl_down(pd,off,32); }
  if (c==0){ asrc[i*8+hd]=ps; adst[i*8+hd]=pd; }
}

// ---------------- per-node attention logits (layer 2) ----------------------
__global__ void k_a(const float* __restrict__ hbuf, const float* __restrict__ att_s,
                    const float* __restrict__ att_d, float* __restrict__ asrc, float* __restrict__ adst){
  int i = blockIdx.x, tid = threadIdx.x, hd = tid>>5, c = tid&31;
  float hv = hbuf[i*256+tid];
  float ps = hv * att_s[tid];
  float pd = hv * att_d[tid];
  for (int off=16; off; off>>=1){ ps += __shfl_down(ps,off,32); pd += __shfl_down(pd,off,32); }
  if (c==0){ asrc[i*8+hd]=ps; adst[i*8+hd]=pd; }
}

// ---------------- GAT online-softmax + aggregate, one block per target -----
__global__ __launch_bounds__(256)
void k_agg(const float* __restrict__ hbuf, const float* __restrict__ asrc,
           const float* __restrict__ adst, const int* __restrict__ csrc,
           const float* __restrict__ cea, const int* __restrict__ starts,
           const int* __restrict__ deg, const float* __restrict__ lattr,
           const float* __restrict__ We, const float* __restrict__ atte,
           const float* __restrict__ bvec, float* __restrict__ xout){
  int t = blockIdx.x, tid = threadIdx.x, hd = tid>>5;
  __shared__ float AE[8], m[8], den[8], alpha[8];
  __shared__ float L[32*8];
  if (tid < 8){
    float s = 0.f;
    for (int c2=0;c2<32;c2++) s += We[tid*32+c2] * atte[tid*32+c2];
    AE[tid] = s;
  }
  __syncthreads();
  int d = deg[t], s0 = starts[t];
  if (tid < 8){
    float aself = asrc[t*8+tid] + adst[t*8+tid] + lattr[t]*AE[tid];
    aself = aself>=0.f ? aself : 0.2f*aself;
    m[tid] = aself; den[tid] = 1.0f;     // self-loop weight = exp(0)
  }
  __syncthreads();
  float acc = hbuf[t*256+tid];           // self contribution, unnormalized
  int el = tid>>3, h2 = tid&7;
  float adt2 = adst[t*8+h2], ae2 = AE[h2];
  for (int e0=0; e0<d; e0+=32){
    int ce = d-e0 < 32 ? d-e0 : 32;
    float lg = -3.4e38f;
    if (el < ce){
      int src = csrc[s0+e0+el];
      float a = asrc[src*8+h2] + adt2 + cea[s0+e0+el]*ae2;
      lg = a>=0.f ? a : 0.2f*a;
    }
    L[el*8+h2] = lg;
    __syncthreads();
    if (tid < 8){
      float mm = m[tid];
      for (int e=0;e<ce;e++) mm = fmaxf(mm, L[e*8+tid]);
      float al = __expf(m[tid]-mm);
      float dd = den[tid]*al;
      for (int e=0;e<ce;e++) dd += __expf(L[e*8+tid]-mm);
      m[tid]=mm; den[tid]=dd; alpha[tid]=al;
    }
    __syncthreads();
    if (el < ce) L[el*8+h2] = __expf(lg - m[h2]);   // unnormalized weight
    __syncthreads();
    acc *= alpha[hd];
    for (int e=0;e<ce;e++){
      int sre = csrc[s0+e0+e];
      acc += L[e*8+hd] * hbuf[sre*256+tid];
    }
    __syncthreads();
  }
  xout[t*256+tid] = fmaxf(acc/den[hd] + bvec[tid], 0.f);
}

// ---------------- S[o,k], K[o] from streaming Wc1 --------------------------
__global__ __launch_bounds__(256)
void k_sk(const float* __restrict__ Wc1, const float* __restrict__ bc1,
          const float* __restrict__ bes, const float* __restrict__ Wweek,
          const float* __restrict__ Wcap, const float* __restrict__ Wveh,
          const int* __restrict__ wd, const int* __restrict__ vh,
          const int* __restrict__ cp, float* ws){
  int o = blockIdx.x, tid = threadIdx.x;
  __shared__ float besf[32];
  __shared__ float red[256];
  if (tid<32) besf[tid] = bes[tid];
  __syncthreads();
  const float* wr = Wc1 + (size_t)o*INLEN;
  const float* UV = ws + WS_UV;
  float sP = 0.f, tP = 0.f;
  for (int idx=tid; idx<16384; idx+=256){        // thread's k-lane fixed: idx&31 == tid&31
    float wv = wr[idx];
    sP += wv;
    tP += wv * (UV[((idx>>5)<<6) + 32 + (idx&31)] + besf[idx&31]);  // v[j,k]+bes[k]
  }
  for (int j=tid; j<512; j+=256) tP += ws[WS_STOPV+j] * wr[17417+j];
  if (tid < 9){
    int g = tid/3, f = tid-g*3;
    float sv = (g==0) ? Wweek[wd[0]*3+f]
             : (g==1) ? Wcap[cp[0]*3+f]
                      : Wveh[vh[0]*3+f];
    tP += sv * wr[17408+tid];
  }
  red[tid] = sP; __syncthreads();
  if (tid<32){ float s=0.f; for (int q=0;q<8;q++) s += red[tid+32*q]; ws[WS_S+o*32+tid] = s; }
  __syncthreads();
  red[tid] = tP; __syncthreads();
  for (int off=128; off; off>>=1){ if (tid<off) red[tid] += red[tid+off]; __syncthreads(); }
  if (tid==0) ws[WS_K+o] = red[0] + bc1[o];
}

// ---------------- pack A (bf16) = [u | dist_norm | markov] -----------------
__global__ void k_packA(const float* __restrict__ dist, const float* __restrict__ markov, float* ws){
  int i = blockIdx.x, tid = threadIdx.x;
  float mn = __int_as_float(((int*)(ws+WS_MM))[0]);
  float mx = __int_as_float(((int*)(ws+WS_MM))[1]);
  float inv = 1.0f/(mx-mn);
  bf16* ap = (bf16*)(ws+WS_APACK);
  for (int j=tid; j<K1; j+=256){
    float v;
    if (j<32)       v = ws[WS_UV + i*64 + j];
    else if (j<544) v = (dist[i*512 + j-32] - mn) * inv;
    else            v = markov[i*512 + j-544];
    ap[(size_t)i*K1 + j] = __float2bfloat16(v);
  }
}

// ------- pack B (bf16) = [S | Wc1_dist | Wc1_markov]; also Wc2 -> bf16 -----
__global__ void k_packB(const float* __restrict__ Wc1, const float* __restrict__ Wc2, float* ws){
  int o = blockIdx.x, tid = threadIdx.x;
  bf16* bp  = (bf16*)(ws+WS_BPACK);
  bf16* w2b = (bf16*)(ws+WS_WC2B);
  for (int j=tid; j<K1; j+=256){
    float v = (j<32) ? ws[WS_S+o*32+j] : Wc1[(size_t)o*INLEN + 16384 + (j-32)];
    bp[(size_t)o*K1 + j] = __float2bfloat16(v);
  }
  for (int j=tid; j<512; j+=256)
    w2b[o*512+j] = __float2bfloat16(Wc2[o*512+j]);
}

// ---------------- f32 GEMM (small shapes): C = A(MxK)·B(NxK)^T -------------
template<bool RELU>
__global__ __launch_bounds__(256)
void gemm32(const float* __restrict__ A, const float* __restrict__ B,
            const float* __restrict__ bias, float* __restrict__ C,
            int M, int Nn, int K){
  __shared__ float As[32][34];
  __shared__ float Bs[32][34];
  const int tid = threadIdx.x;
  const int bm = blockIdx.y*32, bn = blockIdx.x*32;
  const int lr = tid>>3, lq = tid&7;
  const int tx = tid&15, ty = tid>>4;
  float a00=0.f, a01=0.f, a10=0.f, a11=0.f;
  const float* Ab = A + (size_t)(bm+lr)*K + 4*lq;
  const float* Bb = B + (size_t)(bn+lr)*K + 4*lq;
  for (int k0=0; k0<K; k0+=32){
    float4 av = *(const float4*)(Ab + k0);
    float4 bv = *(const float4*)(Bb + k0);
    As[4*lq+0][lr]=av.x; As[4*lq+1][lr]=av.y; As[4*lq+2][lr]=av.z; As[4*lq+3][lr]=av.w;
    Bs[4*lq+0][lr]=bv.x; Bs[4*lq+1][lr]=bv.y; Bs[4*lq+2][lr]=bv.z; Bs[4*lq+3][lr]=bv.w;
    __syncthreads();
    #pragma unroll
    for (int kk=0; kk<32; kk++){
      float2 a2 = *(const float2*)&As[kk][2*ty];
      float2 b2 = *(const float2*)&Bs[kk][2*tx];
      a00 += a2.x*b2.x; a01 += a2.x*b2.y; a10 += a2.y*b2.x; a11 += a2.y*b2.y;
    }
    __syncthreads();
  }
  int m0 = bm+2*ty, n0 = bn+2*tx;
  float bi0 = bias ? bias[n0]   : 0.f;
  float bi1 = bias ? bias[n0+1] : 0.f;
  float v00=a00+bi0, v01=a01+bi1, v10=a10+bi0, v11=a11+bi1;
  if (RELU){ v00=fmaxf(v00,0.f); v01=fmaxf(v01,0.f); v10=fmaxf(v10,0.f); v11=fmaxf(v11,0.f); }
  C[(size_t)m0*Nn+n0]       = v00;
  C[(size_t)m0*Nn+n0+1]     = v01;
  C[(size_t)(m0+1)*Nn+n0]   = v10;
  C[(size_t)(m0+1)*Nn+n0+1] = v11;
}

// ------------- bf16 MFMA GEMM: C = A(MxK)·B(NxK)^T, 64x64 tile -------------
// LDS quad-major layout: tile element [row][q*8+j] stored at [(q*64+row)*8+j]
// so each lane's 8-element fragment is one contiguous 16B ds_read_b128.
template<bool RELU, bool BF16OUT>
__global__ __launch_bounds__(256)
void gemm_mfma(const bf16* __restrict__ A, const bf16* __restrict__ B,
               const float* __restrict__ bias, float* __restrict__ Cf,
               bf16* __restrict__ Cb, int M, int N, int K){
  __shared__ short Als[2048];   // 4KB
  __shared__ short Bls[2048];
  const int tid = threadIdx.x;
  const int bm = blockIdx.y*64, bn = blockIdx.x*64;
  const int wave = tid>>6, lane = tid&63;
  const int wm = wave>>1, wn = wave&1;
  const int r = lane&15, q = lane>>4;
  f32x4 acc[2][2] = {};
  const int lrow = tid>>2, lq = tid&3;
  const bf16* Ag = A + (size_t)(bm+lrow)*K + lq*8;
  const bf16* Bg = B + (size_t)(bn+lrow)*K + lq*8;
  const int sidx = (lq*64+lrow)*8;
  for (int k0=0; k0<K; k0+=32){
    float4 av = *(const float4*)(Ag + k0);
    float4 bv = *(const float4*)(Bg + k0);
    *(float4*)(&Als[sidx]) = av;
    *(float4*)(&Bls[sidx]) = bv;
    __syncthreads();
    #pragma unroll
    for (int i=0;i<2;i++){
      bf16x8 af = *(const bf16x8*)(&Als[(q*64 + wm*32 + i*16 + r)*8]);
      #pragma unroll
      for (int j=0;j<2;j++){
        bf16x8 bfr = *(const bf16x8*)(&Bls[(q*64 + wn*32 + j*16 + r)*8]);
        acc[i][j] = __builtin_amdgcn_mfma_f32_16x16x32_bf16(af, bfr, acc[i][j], 0,0,0);
      }
    }
    __syncthreads();
  }
  #pragma unroll
  for (int i=0;i<2;i++){
    int row = bm + wm*32 + i*16 + q*4;
    #pragma unroll
    for (int j=0;j<2;j++){
      int col = bn + wn*32 + j*16 + r;
      float bi = bias ? bias[col] : 0.f;
      #pragma unroll
      for (int g=0; g<4; g++){
        float v = acc[i][j][g] + bi;
        if (RELU) v = fmaxf(v, 0.f);
        if (BF16OUT) Cb[(size_t)(row+g)*N + col] = __float2bfloat16(v);
        else         Cf[(size_t)(row+g)*N + col] = v;
      }
    }
  }
}

extern "C" void kernel_launch(void* const* d_in, const int* in_sizes, int n_in,
                              void* d_out, int out_size, void* d_ws, size_t ws_size,
                              hipStream_t stream){
  const float* dist   = (const float*)d_in[0];
  const float* markov = (const float*)d_in[1];
  const float* demand = (const float*)d_in[2];
  const float* Wweek  = (const float*)d_in[3];
  const float* Wcap   = (const float*)d_in[4];
  const float* Wveh   = (const float*)d_in[5];
  const float* g1W    = (const float*)d_in[6];
  const float* g1as   = (const float*)d_in[7];
  const float* g1ad   = (const float*)d_in[8];
  const float* g1We   = (const float*)d_in[9];
  const float* g1ae   = (const float*)d_in[10];
  const float* g1b    = (const float*)d_in[11];
  const float* g2W    = (const float*)d_in[12];
  const float* g2as   = (const float*)d_in[13];
  const float* g2ad   = (const float*)d_in[14];
  const float* g2We   = (const float*)d_in[15];
  const float* g2ae   = (const float*)d_in[16];
  const float* g2b    = (const float*)d_in[17];
  const float* Wes    = (const float*)d_in[18];
  const float* bes    = (const float*)d_in[19];
  const float* Wc1    = (const float*)d_in[20];
  const float* bc1    = (const float*)d_in[21];
  const float* Wc2    = (const float*)d_in[22];
  const float* bc2    = (const float*)d_in[23];
  const int*   stops  = (const int*)d_in[24];
  const int*   eidx   = (const int*)d_in[25];
  const int*   wd     = (const int*)d_in[26];
  const int*   vh     = (const int*)d_in[27];
  const int*   cp     = (const int*)d_in[28];
  float* out = (float*)d_out;
  float* ws = (float*)d_ws;

  const int*   csrc   = (const int*)(ws+WS_CSRC);
  const float* cea    = ws+WS_CEA;
  const int*   starts = (const int*)(ws+WS_STARTS);
  const int*   deg    = (const int*)(ws+WS_DEG);
  const float* lattr  = ws+WS_LATTR;

  // graph prep + misc
  k_init<<<1,512,0,stream>>>(ws, stops);
  k_packwes<<<64,256,0,stream>>>(Wes, ws);
  k_minmax<<<256,256,0,stream>>>(dist, ws);
  k_edge<<<64,256,0,stream>>>(eidx, markov, ws);
  k_scan<<<1,512,0,stream>>>(ws);
  k_scatter<<<64,256,0,stream>>>(eidx, ws);

  // GAT layer 1 (input dim 1, rank-1 h)
  k_h1a<<<512,256,0,stream>>>(demand, g1W, g1as, g1ad, ws+WS_H, ws+WS_ASRC, ws+WS_ADST);
  k_agg<<<512,256,0,stream>>>(ws+WS_H, ws+WS_ASRC, ws+WS_ADST, csrc, cea, starts, deg, lattr,
                              g1We, g1ae, g1b, ws+WS_X1);

  // GAT layer 2: h = x1 @ g2W^T
  gemm32<false><<<dim3(8,16),256,0,stream>>>(ws+WS_X1, g2W, nullptr, ws+WS_H, 512, 256, 256);
  k_a<<<512,256,0,stream>>>(ws+WS_H, g2as, g2ad, ws+WS_ASRC, ws+WS_ADST);
  k_agg<<<512,256,0,stream>>>(ws+WS_H, ws+WS_ASRC, ws+WS_ADST, csrc, cea, starts, deg, lattr,
                              g2We, g2ae, g2b, ws+WS_X2);

  // u|v = x2 @ [WesL|WesR]^T  (512x64)
  gemm32<false><<<dim3(2,16),256,0,stream>>>(ws+WS_X2, ws+WS_WESF, nullptr, ws+WS_UV, 512, 64, 256);

  // decoder: S/K fold of Wc1, bf16 packs, two MFMA GEMMs
  k_sk<<<512,256,0,stream>>>(Wc1, bc1, bes, Wweek, Wcap, Wveh, wd, vh, cp, ws);
  k_packA<<<512,256,0,stream>>>(dist, markov, ws);
  k_packB<<<512,256,0,stream>>>(Wc1, Wc2, ws);
  gemm_mfma<true,true><<<dim3(8,8),256,0,stream>>>((const bf16*)(ws+WS_APACK), (const bf16*)(ws+WS_BPACK),
                                                   ws+WS_K, nullptr, (bf16*)(ws+WS_OUT1), 512, 512, K1);
  gemm_mfma<false,false><<<dim3(8,8),256,0,stream>>>((const bf16*)(ws+WS_OUT1), (const bf16*)(ws+WS_WC2B),
                                                     bc2, out, nullptr, 512, 512, 512);
}